// Round 4
// baseline (9067.767 us; speedup 1.0000x reference)
//
#include <hip/hip_runtime.h>
#include <hip/hip_bf16.h>
#include <math.h>
#include <stdio.h>

typedef long long ll;

#define CIN    2
#define COUTC  2
#define Hh     180
#define Ww     360
#define Ech    256
#define NLAYERS 4
#define LMAX   90
#define MMAX   91
#define HIDD   512
#define NPIX   (Hh*Ww)       // 64800
#define CHROWS (Ech*Hh)      // 46080
#define S2     (2*MMAX)      // 182
#define NC     16200         // MLP pixel-chunk (NPIX/4)

// ---------------- generic strided batched GEMM ----------------
// C[z,i,j] = alpha * sum_k A[z,i,k]*B[z,k,j]  (+ Add[z,i,j]) (then gelu)
struct GemmP {
    const float* A; const float* Bm; const float* Dd; float* C;
    ll sAb, sAi, sAk;
    ll sBb, sBk, sBj;
    ll sCb, sCi, sCj;
    ll sDb, sDi, sDj;
    int M, N, K;
    float alpha;
    int epi;   // bit0: add Dd, bit1: gelu (applied after add)
};

#define BM 64
#define BN 64
#define BK 16

__global__ __launch_bounds__(256)
void gemm_f32(GemmP p) {
    __shared__ float As[BM][BK];
    __shared__ float Bs[BK][BN];
    const int t  = threadIdx.x;
    const int tx = t & 15, ty = t >> 4;
    const int z  = blockIdx.z;
    const int i0 = blockIdx.y * BM;
    const int j0 = blockIdx.x * BN;
    const float* Ab = p.A  + (ll)z * p.sAb;
    const float* Bb = p.Bm + (ll)z * p.sBb;
    float acc[4][4] = {};
    for (int kt = 0; kt < p.K; kt += BK) {
#pragma unroll
        for (int s = 0; s < 4; ++s) {
            int idx = t + 256 * s;
            int i = idx >> 4, k = idx & 15;
            int gi = i0 + i, gk = kt + k;
            As[i][k] = (gi < p.M && gk < p.K) ? Ab[(ll)gi * p.sAi + (ll)gk * p.sAk] : 0.0f;
        }
#pragma unroll
        for (int s = 0; s < 4; ++s) {
            int idx = t + 256 * s;
            int k = idx >> 6, j = idx & 63;
            int gk = kt + k, gj = j0 + j;
            Bs[k][j] = (gk < p.K && gj < p.N) ? Bb[(ll)gk * p.sBk + (ll)gj * p.sBj] : 0.0f;
        }
        __syncthreads();
#pragma unroll
        for (int kk = 0; kk < BK; ++kk) {
            float a[4], b[4];
#pragma unroll
            for (int ii = 0; ii < 4; ++ii) a[ii] = As[ty + 16*ii][kk];
#pragma unroll
            for (int jj = 0; jj < 4; ++jj) b[jj] = Bs[kk][tx + 16*jj];
#pragma unroll
            for (int ii = 0; ii < 4; ++ii)
#pragma unroll
                for (int jj = 0; jj < 4; ++jj)
                    acc[ii][jj] += a[ii] * b[jj];
        }
        __syncthreads();
    }
    float* Cb = p.C + (ll)z * p.sCb;
    const float* Db = p.Dd ? (p.Dd + (ll)z * p.sDb) : nullptr;
#pragma unroll
    for (int ii = 0; ii < 4; ++ii) {
        int gi = i0 + ty + 16*ii;
        if (gi >= p.M) continue;
#pragma unroll
        for (int jj = 0; jj < 4; ++jj) {
            int gj = j0 + tx + 16*jj;
            if (gj >= p.N) continue;
            float r = p.alpha * acc[ii][jj];
            if (p.epi & 1) r += Db[(ll)gi * p.sDi + (ll)gj * p.sDj];
            if (p.epi & 2) r = 0.5f * r * (1.0f + erff(r * 0.70710678118654752f));
            Cb[(ll)gi * p.sCi + (ll)gj * p.sCj] = r;
        }
    }
}

// ---------------- batched tiled transpose ----------------
// dst[b, c, r] = src[b, r, c]; unit stride on src col and dst row.
__global__ __launch_bounds__(256)
void transp_k(const float* __restrict__ src, float* __restrict__ dst, int R, int C,
              ll srcB, ll srcR, ll dstB, ll dstR) {
    __shared__ float tile[32][33];
    ll b = blockIdx.z;
    int r0 = blockIdx.y * 32, c0 = blockIdx.x * 32;
    const float* s = src + b * srcB;
    float* d = dst + b * dstB;
    int tx = threadIdx.x, ty = threadIdx.y;   // 32 x 8
    for (int k = 0; k < 32; k += 8) {
        int r = r0 + ty + k, c = c0 + tx;
        if (r < R && c < C) tile[ty + k][tx] = s[(ll)r * srcR + c];
    }
    __syncthreads();
    for (int k = 0; k < 32; k += 8) {
        int c = c0 + ty + k, r = r0 + tx;
        if (r < R && c < C) d[(ll)c * dstR + r] = tile[tx][ty + k];
    }
}

// ---------------- setup kernels ----------------
__global__ void build_dft(float* __restrict__ D, float* __restrict__ Dinv) {
    int idx = blockIdx.x * blockDim.x + threadIdx.x;
    if (idx >= Ww * MMAX) return;
    int w = idx / MMAX, m = idx % MMAX;
    int prod = (w * m) % Ww;
    float ang = (2.0f * (float)M_PI / (float)Ww) * (float)prod;
    float cv = cosf(ang), sv = sinf(ang);
    // forward rfft: X[m] = sum_w x[w] (cos - i sin)
    D[(ll)w * S2 + m]        = cv;
    D[(ll)w * S2 + MMAX + m] = -sv;
    // inverse: x[w] = (1/W)[X0_r + sum_{m>=1} 2(Xr cos - Xi sin)], bin0 imag ignored
    float scale = (m == 0) ? (1.0f / (float)Ww) : (2.0f / (float)Ww);
    Dinv[(ll)m * Ww + w]          = scale * cv;
    Dinv[(ll)(MMAX + m) * Ww + w] = (m == 0) ? 0.0f : -scale * sv;
}

__global__ void dup_setup(const float* __restrict__ leg_inv, float* __restrict__ LI2,
                          float* __restrict__ LFT2) {
    int idx = blockIdx.x * blockDim.x + threadIdx.x;
    const int n = MMAX * LMAX * Hh;   // 1474200
    if (idx < n) {
        float v = leg_inv[idx];
        LI2[idx]     = v;
        LI2[n + idx] = v;
        LFT2[n + idx] = LFT2[idx];   // duplicate already-transposed lower half
    }
}

// ---------------- host helpers ----------------
static inline void gemm(hipStream_t st, const float* A, const float* B, float* C, const float* Add,
                        int M, int N, int K, int nb,
                        ll sAb, ll sAi, ll sAk,
                        ll sBb, ll sBk, ll sBj,
                        ll sCb, ll sCi, ll sCj,
                        ll sDb, ll sDi, ll sDj,
                        float alpha, int epi) {
    GemmP p{A, B, Add, C, sAb, sAi, sAk, sBb, sBk, sBj, sCb, sCi, sCj, sDb, sDi, sDj,
            M, N, K, alpha, epi};
    dim3 g((N + BN - 1) / BN, (M + BM - 1) / BM, nb);
    gemm_f32<<<g, dim3(256), 0, st>>>(p);
}

static inline void transp(hipStream_t st, const float* src, float* dst, int R, int C,
                          ll srcB, ll srcR, ll dstB, ll dstR, int nb) {
    dim3 g((C + 31) / 32, (R + 31) / 32, nb);
    transp_k<<<g, dim3(32, 8), 0, st>>>(src, dst, R, C, srcB, srcR, dstB, dstR);
}

extern "C" void kernel_launch(void* const* d_in, const int* in_sizes, int n_in,
                              void* d_out, int out_size, void* d_ws, size_t ws_size,
                              hipStream_t stream) {
    const float* x        = (const float*)d_in[0];
    const float* enc_w1   = (const float*)d_in[1];
    const float* enc_w2   = (const float*)d_in[2];
    const float* pos      = (const float*)d_in[3];
    const float* leg_fwd  = (const float*)d_in[4];
    const float* leg_inv  = (const float*)d_in[5];
    const float* w_spec_r = (const float*)d_in[6];
    const float* w_spec_i = (const float*)d_in[7];
    const float* w_inner  = (const float*)d_in[8];
    const float* w_mlp1   = (const float*)d_in[9];
    const float* w_mlp2   = (const float*)d_in[10];
    const float* dec_w1   = (const float*)d_in[11];
    const float* dec_w2   = (const float*)d_in[12];
    float* out = (float*)d_out;

    float* wsp = (float*)d_ws;
    ll off = 0;
    auto alloc = [&](ll n) { float* p = wsp + off; off += n; return p; };

    float* Dm   = alloc((ll)Ww * S2);            // [360][182] fwd DFT (cos | -sin)
    float* Dinv = alloc((ll)S2 * Ww);            // [182][360] inverse DFT
    float* LFT2 = alloc((ll)2 * MMAX * Hh * LMAX); // [182][180][90]  leg_fwd^T duplicated
    float* LI2  = alloc((ll)2 * MMAX * LMAX * Hh); // [182][90][180]  leg_inv duplicated
    float* WTr  = alloc((ll)LMAX * Ech * Ech);   // [90][256][256]
    float* WTi  = alloc((ll)LMAX * Ech * Ech);
    float* XF   = alloc((ll)CHROWS * S2);        // [46080][182]  (also YF)
    float* XT   = alloc((ll)S2 * CHROWS);        // [182][256][180] (also YT)
    float* CF   = alloc((ll)S2 * Ech * LMAX);    // [182][256][90] (also COT)
    float* TCF  = alloc((ll)2 * LMAX * Ech * MMAX); // [2][90][256][91]
    float* CO   = alloc((ll)2 * LMAX * Ech * MMAX); // [2][90][256][91]
    float* Hb   = alloc((ll)Ech * NPIX);
    float* Vb   = alloc((ll)Ech * NPIX);
    float* Gb   = alloc((ll)HIDD * NC);          // MLP hidden, quarter-pixel chunks

    if ((size_t)(off * 4) > ws_size) {
        fprintf(stderr, "kernel_launch: ws too small: need %lld bytes, have %zu\n",
                off * 4, ws_size);
        return;
    }

    const ll EE = (ll)Ech * Ech;

    // ---- setup: DFT matrices, transposed/duplicated Legendre matrices ----
    build_dft<<<dim3((Ww * MMAX + 255) / 256), dim3(256), 0, stream>>>(Dm, Dinv);
    // leg_fwd [m][l][h] -> LFT2 [m][h][l]  (lower half)
    transp(stream, leg_fwd, LFT2, LMAX, Hh, (ll)LMAX * Hh, (ll)Hh, (ll)Hh * LMAX, (ll)LMAX, MMAX);
    dup_setup<<<dim3((MMAX * LMAX * Hh + 255) / 256), dim3(256), 0, stream>>>(leg_inv, LI2, LFT2);

    // ---- encoder ----
    // V = gelu(enc_w1 @ x)
    gemm(stream, enc_w1, x, Vb, nullptr, Ech, NPIX, CIN, 1,
         0, CIN, 1,  0, NPIX, 1,  0, NPIX, 1,  0, 0, 0,  1.0f, 2);
    // H = enc_w2 @ V + pos
    gemm(stream, enc_w2, Vb, Hb, pos, Ech, NPIX, Ech, 1,
         0, Ech, 1,  0, NPIX, 1,  0, NPIX, 1,  0, NPIX, 1,  1.0f, 1);

    float* curH = Hb;
    float* curV = Vb;

    for (int l = 0; l < NLAYERS; ++l) {
        // transpose spectral weights: w_spec[l][o][c][lm] -> WT[lm][o][c]
        transp(stream, w_spec_r + (ll)l * EE * LMAX, WTr, Ech, LMAX,
               (ll)Ech * LMAX, (ll)LMAX, (ll)Ech, EE, Ech);
        transp(stream, w_spec_i + (ll)l * EE * LMAX, WTi, Ech, LMAX,
               (ll)Ech * LMAX, (ll)LMAX, (ll)Ech, EE, Ech);

        // rfft: XF[(c,h)][s] = H[(c,h)][w] @ D[w][s]
        gemm(stream, curH, Dm, XF, nullptr, CHROWS, S2, Ww, 1,
             0, Ww, 1,  0, S2, 1,  0, S2, 1,  0, 0, 0,  1.0f, 0);

        // XF -> XT [s][(c,h)]
        transp(stream, XF, XT, CHROWS, S2, 0, (ll)S2, 0, (ll)CHROWS, 1);

        // Legendre fwd: CF[s][c][lm] = XT[s][c][h] @ LFT2[s][h][lm]
        gemm(stream, XT, LFT2, CF, nullptr, Ech, LMAX, Hh, S2,
             (ll)CHROWS, (ll)Hh, 1,
             (ll)Hh * LMAX, (ll)LMAX, 1,
             (ll)Ech * LMAX, (ll)LMAX, 1,
             0, 0, 0, 1.0f, 0);

        // CF[(p,m)][c][lm] -> TCF[p][lm][c][m]
        for (int ppart = 0; ppart < 2; ++ppart)
            transp(stream, CF + (ll)ppart * MMAX * Ech * LMAX,
                   TCF + (ll)ppart * LMAX * Ech * MMAX,
                   MMAX, LMAX, (ll)LMAX, (ll)Ech * LMAX, (ll)MMAX, (ll)Ech * MMAX, Ech);

        // complex spectral filter, batch over lm:
        float* COr = CO;
        float* COi = CO + (ll)LMAX * Ech * MMAX;
        const float* TCFr = TCF;
        const float* TCFi = TCF + (ll)LMAX * Ech * MMAX;
        // COr = WTr@TCFr
        gemm(stream, WTr, TCFr, COr, nullptr, Ech, MMAX, Ech, LMAX,
             EE, Ech, 1,  (ll)Ech * MMAX, MMAX, 1,  (ll)Ech * MMAX, MMAX, 1,  0, 0, 0, 1.0f, 0);
        // COr += -WTi@TCFi
        gemm(stream, WTi, TCFi, COr, COr, Ech, MMAX, Ech, LMAX,
             EE, Ech, 1,  (ll)Ech * MMAX, MMAX, 1,  (ll)Ech * MMAX, MMAX, 1,
             (ll)Ech * MMAX, MMAX, 1, -1.0f, 1);
        // COi = WTr@TCFi
        gemm(stream, WTr, TCFi, COi, nullptr, Ech, MMAX, Ech, LMAX,
             EE, Ech, 1,  (ll)Ech * MMAX, MMAX, 1,  (ll)Ech * MMAX, MMAX, 1,  0, 0, 0, 1.0f, 0);
        // COi += WTi@TCFr
        gemm(stream, WTi, TCFr, COi, COi, Ech, MMAX, Ech, LMAX,
             EE, Ech, 1,  (ll)Ech * MMAX, MMAX, 1,  (ll)Ech * MMAX, MMAX, 1,
             (ll)Ech * MMAX, MMAX, 1, 1.0f, 1);

        // CO[p][lm][o][m] -> COT[(p,m)][o][lm]   (COT reuses CF buffer)
        float* COT = CF;
        for (int ppart = 0; ppart < 2; ++ppart)
            transp(stream, CO + (ll)ppart * LMAX * Ech * MMAX,
                   COT + (ll)ppart * MMAX * Ech * LMAX,
                   LMAX, MMAX, (ll)MMAX, (ll)Ech * MMAX, (ll)LMAX, (ll)Ech * LMAX, Ech);

        // Legendre inv: YT[s][o][h] = COT[s][o][lm] @ LI2[s][lm][h]   (YT reuses XT)
        float* YT = XT;
        gemm(stream, COT, LI2, YT, nullptr, Ech, Hh, LMAX, S2,
             (ll)Ech * LMAX, (ll)LMAX, 1,
             (ll)LMAX * Hh, (ll)Hh, 1,
             (ll)Ech * Hh, (ll)Hh, 1,
             0, 0, 0, 1.0f, 0);

        // YT[s][(o,h)] -> YF[(o,h)][s]   (YF reuses XF)
        float* YF = XF;
        transp(stream, YT, YF, S2, CHROWS, 0, (ll)CHROWS, 0, (ll)S2, 1);

        // irfft: V[(c,h)][w] = YF[(c,h)][s] @ Dinv[s][w]
        gemm(stream, YF, Dinv, curV, nullptr, CHROWS, Ww, S2, 1,
             0, S2, 1,  0, Ww, 1,  0, Ww, 1,  0, 0, 0,  1.0f, 0);

        // inner skip: V += w_inner[l] @ H
        gemm(stream, w_inner + (ll)l * EE, curH, curV, curV, Ech, NPIX, Ech, 1,
             0, Ech, 1,  0, NPIX, 1,  0, NPIX, 1,  0, NPIX, 1,  1.0f, 1);

        // MLP in four pixel chunks; then V = mlp2@G + H (residual)
        for (int c0 = 0; c0 < NPIX; c0 += NC) {
            gemm(stream, w_mlp1 + (ll)l * HIDD * Ech, curV + c0, Gb, nullptr,
                 HIDD, NC, Ech, 1,
                 0, Ech, 1,  0, NPIX, 1,  0, NC, 1,  0, 0, 0,  1.0f, 2);
            gemm(stream, w_mlp2 + (ll)l * Ech * HIDD, Gb, curV + c0, curH + c0,
                 Ech, NC, HIDD, 1,
                 0, HIDD, 1,  0, NC, 1,  0, NPIX, 1,  0, NPIX, 1,  1.0f, 1);
        }

        // swap roles
        float* tmp = curH; curH = curV; curV = tmp;
    }

    // ---- decoder ----
    // After an even number of swaps curH is the live buffer; curV is dead scratch.
    float* T2 = curV;   // [256][64800]
    // T2 = dec_w1[:, :256] @ H
    gemm(stream, dec_w1, curH, T2, nullptr, Ech, NPIX, Ech, 1,
         0, Ech + CIN, 1,  0, NPIX, 1,  0, NPIX, 1,  0, 0, 0,  1.0f, 0);
    // T2 = gelu(dec_w1[:, 256:] @ x + T2)
    gemm(stream, dec_w1 + Ech, x, T2, T2, Ech, NPIX, CIN, 1,
         0, Ech + CIN, 1,  0, NPIX, 1,  0, NPIX, 1,  0, NPIX, 1,  1.0f, 3);
    // out = dec_w2 @ T2
    gemm(stream, dec_w2, T2, out, nullptr, COUTC, NPIX, Ech, 1,
         0, Ech, 1,  0, NPIX, 1,  0, NPIX, 1,  0, 0, 0,  1.0f, 0);
}

// Round 5
// 2860.662 us; speedup vs baseline: 3.1698x; 3.1698x over previous
//
#include <hip/hip_runtime.h>
#include <hip/hip_bf16.h>
#include <math.h>
#include <stdio.h>

typedef long long ll;
typedef __bf16 bf16x8 __attribute__((ext_vector_type(8)));
typedef float f32x4 __attribute__((ext_vector_type(4)));

#define CIN    2
#define COUTC  2
#define Hh     180
#define Ww     360
#define Ech    256
#define NLAYERS 4
#define LMAX   90
#define MMAX   91
#define HIDD   512
#define NPIX   (Hh*Ww)       // 64800
#define CHROWS (Ech*Hh)      // 46080
#define S2     (2*MMAX)      // 182
#define CDIV(a,b) (((a)+(b)-1)/(b))

// ================= bf16 MFMA GEMM (both operands k-contiguous) =================
// C[z,i,j] = sum_k A[z,i,k]*B[z,j,k]   (B supplied transposed: [N][K])
// K must be a multiple of 32. ldA/ldB multiples of 8 (16B rows). Edges on M,N guarded.
struct GemmBP {
    const __hip_bfloat16* A; const __hip_bfloat16* B;
    const float* Dd; void* C;
    ll sAb; int ldA;
    ll sBb; int ldB;
    ll sCb, sCi, sCj;
    ll sDb, sDi, sDj;
    int M, N, K;
    int epi;   // bit0: +Dd, bit1: gelu, bit2: store bf16
};

__device__ __forceinline__ void glds16(const __hip_bfloat16* g, __hip_bfloat16* l) {
    __builtin_amdgcn_global_load_lds(
        (const __attribute__((address_space(1))) unsigned int*)g,
        (__attribute__((address_space(3))) unsigned int*)l,
        16, 0, 0);
}

__global__ __launch_bounds__(256)
void gemm_bf(GemmBP p) {
    // LDS layout: [kg(4)][row(128)][8 elems] for both A and B tiles (16KB total)
    __shared__ __hip_bfloat16 As[4096];
    __shared__ __hip_bfloat16 Bs[4096];
    const int t = threadIdx.x;
    const int lane = t & 63, wv = t >> 6;
    const int wr = wv >> 1, wc = wv & 1;
    const int z = blockIdx.z;
    const int i0 = blockIdx.y * 128, j0 = blockIdx.x * 128;
    const __hip_bfloat16* Ab = p.A + (ll)z * p.sAb;
    const __hip_bfloat16* Bb = p.B + (ll)z * p.sBb;

    f32x4 acc[4][4] = {};

    // staging role per wave: w0: A kg0-1, w1: A kg2-3, w2: B kg0-1, w3: B kg2-3
    const bool isB = (wv >= 2);
    const int kgbase = (wv & 1) * 2;
    const __hip_bfloat16* Gp = isB ? Bb : Ab;
    const int ld  = isB ? p.ldB : p.ldA;
    const int lim = isB ? p.N : p.M;
    const int rb0 = isB ? j0 : i0;
    __hip_bfloat16* Ls = isB ? Bs : As;

    for (int kt = 0; kt < p.K; kt += 32) {
        __syncthreads();                 // protect LDS from previous iter readers
#pragma unroll
        for (int s = 0; s < 4; ++s) {
            int kg = kgbase + (s >> 1), half = s & 1;
            int r = half * 64 + lane;
            int grow = rb0 + r;
            __hip_bfloat16* ldst = Ls + kg * 1024 + half * 512;   // +lane*8 implicit
            const __hip_bfloat16* gsrc = Gp + (ll)grow * ld + kt + kg * 8;
            if (grow < lim) glds16(gsrc, ldst);
        }
        __syncthreads();                 // barrier drains vmcnt (staging complete)

        bf16x8 af[4], bg[4];
#pragma unroll
        for (int f = 0; f < 4; ++f) {
            af[f] = *(const bf16x8*)(As + (lane >> 4) * 1024 + (wr * 64 + f * 16 + (lane & 15)) * 8);
            bg[f] = *(const bf16x8*)(Bs + (lane >> 4) * 1024 + (wc * 64 + f * 16 + (lane & 15)) * 8);
        }
#pragma unroll
        for (int fr = 0; fr < 4; ++fr)
#pragma unroll
            for (int fn = 0; fn < 4; ++fn)
                acc[fr][fn] = __builtin_amdgcn_mfma_f32_16x16x32_bf16(af[fr], bg[fn], acc[fr][fn], 0, 0, 0);
    }

    float* Cf = (float*)p.C;
    __hip_bfloat16* Ch = (__hip_bfloat16*)p.C;
    const float* Db = p.Dd ? (p.Dd + (ll)z * p.sDb) : nullptr;
    const ll cb = (ll)z * p.sCb;
#pragma unroll
    for (int fr = 0; fr < 4; ++fr) {
#pragma unroll
        for (int j = 0; j < 4; ++j) {
            int row = i0 + wr * 64 + fr * 16 + (lane >> 4) * 4 + j;
            if (row >= p.M) continue;
#pragma unroll
            for (int fn = 0; fn < 4; ++fn) {
                int col = j0 + wc * 64 + fn * 16 + (lane & 15);
                if (col >= p.N) continue;
                float r = acc[fr][fn][j];
                if (p.epi & 1) r += Db[(ll)row * p.sDi + (ll)col * p.sDj];
                if (p.epi & 2) r = 0.5f * r * (1.0f + erff(r * 0.70710678118654752f));
                ll ca = cb + (ll)row * p.sCi + (ll)col * p.sCj;
                if (p.epi & 4) Ch[ca] = __hip_bfloat16(r);
                else           Cf[ca] = r;
            }
        }
    }
}

// ================= fp32 GEMM (kept for K=2 encoder/decoder paths) =================
struct GemmP {
    const float* A; const float* Bm; const float* Dd; float* C;
    ll sAb, sAi, sAk;
    ll sBb, sBk, sBj;
    ll sCb, sCi, sCj;
    ll sDb, sDi, sDj;
    int M, N, K;
    float alpha;
    int epi;
};

#define BM 64
#define BN 64
#define BK 16

__global__ __launch_bounds__(256)
void gemm_f32(GemmP p) {
    __shared__ float As[BM][BK];
    __shared__ float Bs[BK][BN];
    const int t  = threadIdx.x;
    const int tx = t & 15, ty = t >> 4;
    const int z  = blockIdx.z;
    const int i0 = blockIdx.y * BM;
    const int j0 = blockIdx.x * BN;
    const float* Ab = p.A  + (ll)z * p.sAb;
    const float* Bb = p.Bm + (ll)z * p.sBb;
    float acc[4][4] = {};
    for (int kt = 0; kt < p.K; kt += BK) {
#pragma unroll
        for (int s = 0; s < 4; ++s) {
            int idx = t + 256 * s;
            int i = idx >> 4, k = idx & 15;
            int gi = i0 + i, gk = kt + k;
            As[i][k] = (gi < p.M && gk < p.K) ? Ab[(ll)gi * p.sAi + (ll)gk * p.sAk] : 0.0f;
        }
#pragma unroll
        for (int s = 0; s < 4; ++s) {
            int idx = t + 256 * s;
            int k = idx >> 6, j = idx & 63;
            int gk = kt + k, gj = j0 + j;
            Bs[k][j] = (gk < p.K && gj < p.N) ? Bb[(ll)gk * p.sBk + (ll)gj * p.sBj] : 0.0f;
        }
        __syncthreads();
#pragma unroll
        for (int kk = 0; kk < BK; ++kk) {
            float a[4], b[4];
#pragma unroll
            for (int ii = 0; ii < 4; ++ii) a[ii] = As[ty + 16*ii][kk];
#pragma unroll
            for (int jj = 0; jj < 4; ++jj) b[jj] = Bs[kk][tx + 16*jj];
#pragma unroll
            for (int ii = 0; ii < 4; ++ii)
#pragma unroll
                for (int jj = 0; jj < 4; ++jj)
                    acc[ii][jj] += a[ii] * b[jj];
        }
        __syncthreads();
    }
    float* Cb = p.C + (ll)z * p.sCb;
    const float* Db = p.Dd ? (p.Dd + (ll)z * p.sDb) : nullptr;
#pragma unroll
    for (int ii = 0; ii < 4; ++ii) {
        int gi = i0 + ty + 16*ii;
        if (gi >= p.M) continue;
#pragma unroll
        for (int jj = 0; jj < 4; ++jj) {
            int gj = j0 + tx + 16*jj;
            if (gj >= p.N) continue;
            float r = p.alpha * acc[ii][jj];
            if (p.epi & 1) r += Db[(ll)gi * p.sDi + (ll)gj * p.sDj];
            if (p.epi & 2) r = 0.5f * r * (1.0f + erff(r * 0.70710678118654752f));
            Cb[(ll)gi * p.sCi + (ll)gj * p.sCj] = r;
        }
    }
}

// ================= transpose + fp32->bf16 convert (with sign) =================
// dst[b*dstB + c*dstR + r] = sign * src[b*srcB + r*srcR + c]   (strides in elements)
__global__ __launch_bounds__(256)
void transp_cv(const float* __restrict__ src, __hip_bfloat16* __restrict__ dst, int R, int C,
               ll srcB, ll srcR, ll dstB, ll dstR, float sign) {
    __shared__ float tile[32][33];
    ll b = blockIdx.z;
    int r0 = blockIdx.y * 32, c0 = blockIdx.x * 32;
    const float* s = src + b * srcB;
    __hip_bfloat16* d = dst + b * dstB;
    int tx = threadIdx.x, ty = threadIdx.y;   // 32 x 8
    for (int k = 0; k < 32; k += 8) {
        int r = r0 + ty + k, c = c0 + tx;
        if (r < R && c < C) tile[ty + k][tx] = s[(ll)r * srcR + c];
    }
    __syncthreads();
    for (int k = 0; k < 32; k += 8) {
        int c = c0 + ty + k, r = r0 + tx;
        if (r < R && c < C) d[(ll)c * dstR + r] = __hip_bfloat16(sign * tile[tx][ty + k]);
    }
}

// ================= small utility kernels =================
__global__ void conv_pad(const float* __restrict__ src, __hip_bfloat16* __restrict__ dst,
                         int R, int Cu, int Cp) {
    ll idx = (ll)blockIdx.x * blockDim.x + threadIdx.x;
    if (idx >= (ll)R * Cp) return;
    int r = (int)(idx / Cp), c = (int)(idx % Cp);
    dst[idx] = (c < Cu) ? __hip_bfloat16(src[(ll)r * Cu + c]) : __hip_bfloat16(0.0f);
}

__global__ void conv_mat(const float* __restrict__ src, __hip_bfloat16* __restrict__ dst,
                         int R, int C, int srcLd) {
    ll idx = (ll)blockIdx.x * blockDim.x + threadIdx.x;
    if (idx >= (ll)R * C) return;
    int r = (int)(idx / C), c = (int)(idx % C);
    dst[idx] = __hip_bfloat16(src[(ll)r * srcLd + c]);
}

__global__ void zero_pad(__hip_bfloat16* __restrict__ dst, ll rows, int ld, int c0, int c1) {
    ll idx = (ll)blockIdx.x * blockDim.x + threadIdx.x;
    int w = c1 - c0;
    if (idx >= rows * w) return;
    ll r = idx / w; int c = c0 + (int)(idx % w);
    dst[r * ld + c] = __hip_bfloat16(0.0f);
}

__global__ void build_dmt(__hip_bfloat16* __restrict__ DmT) {
    int idx = blockIdx.x * blockDim.x + threadIdx.x;
    if (idx >= S2 * 384) return;
    int s = idx / 384, w = idx % 384;
    float v = 0.0f;
    if (w < Ww) {
        int m = s % MMAX;
        float ang = (2.0f * (float)M_PI / (float)Ww) * (float)((w * m) % Ww);
        v = (s < MMAX) ? cosf(ang) : -sinf(ang);
    }
    DmT[idx] = __hip_bfloat16(v);
}

__global__ void build_dinvt(__hip_bfloat16* __restrict__ DinvT) {
    int idx = blockIdx.x * blockDim.x + threadIdx.x;
    if (idx >= Ww * 192) return;
    int w = idx / 192, s = idx % 192;
    float v = 0.0f;
    if (s < S2) {
        int m = s % MMAX;
        float ang = (2.0f * (float)M_PI / (float)Ww) * (float)((w * m) % Ww);
        float scale = (m == 0) ? (1.0f / (float)Ww) : (2.0f / (float)Ww);
        if (s < MMAX) v = scale * cosf(ang);
        else          v = (m == 0) ? 0.0f : -scale * sinf(ang);
    }
    DinvT[idx] = __hip_bfloat16(v);
}

__global__ void build_lf(const float* __restrict__ leg_fwd, __hip_bfloat16* __restrict__ LF) {
    int idx = blockIdx.x * blockDim.x + threadIdx.x;
    if (idx >= S2 * LMAX * 192) return;
    int s = idx / (LMAX * 192);
    int rem = idx % (LMAX * 192);
    int l = rem / 192, h = rem % 192;
    float v = (h < Hh) ? leg_fwd[(ll)(s % MMAX) * LMAX * Hh + (ll)l * Hh + h] : 0.0f;
    LF[idx] = __hip_bfloat16(v);
}

__global__ void build_lit(const float* __restrict__ leg_inv, __hip_bfloat16* __restrict__ LIT) {
    int idx = blockIdx.x * blockDim.x + threadIdx.x;
    if (idx >= MMAX * Hh * 96) return;
    int m = idx / (Hh * 96);
    int rem = idx % (Hh * 96);
    int h = rem / 96, l = rem % 96;
    float v = (l < LMAX) ? leg_inv[(ll)m * LMAX * Hh + (ll)l * Hh + h] : 0.0f;
    LIT[idx] = __hip_bfloat16(v);
}

// ================= host helpers =================
static inline void gemmb(hipStream_t st, const __hip_bfloat16* A, int ldA, ll sAb,
                         const __hip_bfloat16* B, int ldB, ll sBb,
                         void* C, ll sCb, ll sCi, ll sCj,
                         const float* Dd, ll sDb, ll sDi, ll sDj,
                         int M, int N, int K, int nb, int epi) {
    GemmBP p{A, B, Dd, C, sAb, ldA, sBb, ldB, sCb, sCi, sCj, sDb, sDi, sDj, M, N, K, epi};
    dim3 g(CDIV(N, 128), CDIV(M, 128), nb);
    gemm_bf<<<g, dim3(256), 0, st>>>(p);
}

static inline void gemm(hipStream_t st, const float* A, const float* B, float* C, const float* Add,
                        int M, int N, int K, int nb,
                        ll sAb, ll sAi, ll sAk,
                        ll sBb, ll sBk, ll sBj,
                        ll sCb, ll sCi, ll sCj,
                        ll sDb, ll sDi, ll sDj,
                        float alpha, int epi) {
    GemmP p{A, B, Add, C, sAb, sAi, sAk, sBb, sBk, sBj, sCb, sCi, sCj, sDb, sDi, sDj,
            M, N, K, alpha, epi};
    dim3 g(CDIV(N, BN), CDIV(M, BM), nb);
    gemm_f32<<<g, dim3(256), 0, st>>>(p);
}

static inline void tcv(hipStream_t st, const float* src, __hip_bfloat16* dst, int R, int C,
                       ll srcB, ll srcR, ll dstB, ll dstR, int nb, float sign) {
    dim3 g(CDIV(C, 32), CDIV(R, 32), nb);
    transp_cv<<<g, dim3(32, 8), 0, st>>>(src, dst, R, C, srcB, srcR, dstB, dstR, sign);
}

extern "C" void kernel_launch(void* const* d_in, const int* in_sizes, int n_in,
                              void* d_out, int out_size, void* d_ws, size_t ws_size,
                              hipStream_t stream) {
    const float* x        = (const float*)d_in[0];
    const float* enc_w1   = (const float*)d_in[1];
    const float* enc_w2   = (const float*)d_in[2];
    const float* pos      = (const float*)d_in[3];
    const float* leg_fwd  = (const float*)d_in[4];
    const float* leg_inv  = (const float*)d_in[5];
    const float* w_spec_r = (const float*)d_in[6];
    const float* w_spec_i = (const float*)d_in[7];
    const float* w_inner  = (const float*)d_in[8];
    const float* w_mlp1   = (const float*)d_in[9];
    const float* w_mlp2   = (const float*)d_in[10];
    const float* dec_w1   = (const float*)d_in[11];
    const float* dec_w2   = (const float*)d_in[12];
    float* out = (float*)d_out;
    float* wsp = (float*)d_ws;

    // ---------------- workspace map (float offsets) ----------------
    // pool (transient, aliased by lifetime):
    float* pool = wsp;
    __hip_bfloat16* HCB  = (__hip_bfloat16*)(pool + 0);          // [46080][384] bf16
    float*          XF   = pool + 8847360;                        // [46080][182] f32
    __hip_bfloat16* XT   = (__hip_bfloat16*)(pool + 0);          // [182][256][192] bf16
    float*          CF   = pool + 8847360;                        // [182][256][90] f32
    __hip_bfloat16* TCF  = (__hip_bfloat16*)(pool + 4472832);    // [90][91][512] bf16
    __hip_bfloat16* WC   = (__hip_bfloat16*)(pool + 13040640);   // [90][512][512] bf16
    float*          CO   = pool + 0;                              // [90][512][91] f32
    __hip_bfloat16* COT  = (__hip_bfloat16*)(pool + 8847360);    // [91][512][96] bf16
    float*          YT   = pool + 0;                              // [91][512][180] f32
    __hip_bfloat16* YF   = (__hip_bfloat16*)(pool + 8847360);    // [46080][192] bf16
    float*          VF   = pool + 13271040;                       // [256][64800] f32 (also V2C, T2a/T2)
    __hip_bfloat16* HPB  = (__hip_bfloat16*)(pool + 0);          // [64800][256] bf16
    __hip_bfloat16* V2PB = (__hip_bfloat16*)(pool + 0);          // [64800][256] bf16
    __hip_bfloat16* GT   = (__hip_bfloat16*)(pool + 8294400);    // [64800][512] bf16
    float*          V1   = pool + 0;                              // encoder tmp [256][64800] f32
    __hip_bfloat16* V1PB = (__hip_bfloat16*)(pool + 16588800);   // [64800][256] bf16
    const ll POOLSZ = 29859840;

    // persistent:
    ll off = POOLSZ;
    float* HC  = wsp + off; off += 16588800;
    float* HC2 = wsp + off; off += 16588800;
    __hip_bfloat16* DmT   = (__hip_bfloat16*)(wsp + off); off += 34944;    // [182][384]
    __hip_bfloat16* DinvT = (__hip_bfloat16*)(wsp + off); off += 34560;    // [360][192]
    __hip_bfloat16* LF    = (__hip_bfloat16*)(wsp + off); off += 1572480;  // [182][90][192]
    __hip_bfloat16* LIT   = (__hip_bfloat16*)(wsp + off); off += 786240;   // [91][180][96]
    __hip_bfloat16* ENC2B = (__hip_bfloat16*)(wsp + off); off += 32768;    // [256][256]
    __hip_bfloat16* WINB  = (__hip_bfloat16*)(wsp + off); off += 32768;    // [256][256]
    __hip_bfloat16* WM1B  = (__hip_bfloat16*)(wsp + off); off += 65536;    // [512][256]
    __hip_bfloat16* WM2B  = (__hip_bfloat16*)(wsp + off); off += 65536;    // [256][512]
    __hip_bfloat16* DW1B  = (__hip_bfloat16*)(wsp + off); off += 32768;    // [256][256]
    __hip_bfloat16* DW2B  = (__hip_bfloat16*)(wsp + off); off += 256;      // [2][256]

    if ((size_t)(off * 4) > ws_size) {
        fprintf(stderr, "kernel_launch: ws too small: need %lld bytes, have %zu\n",
                off * 4, ws_size);
        return;
    }

    const ll EE = (ll)Ech * Ech;

    // ---------------- setup ----------------
    build_dmt  <<<CDIV(S2 * 384, 256), 256, 0, stream>>>(DmT);
    build_dinvt<<<CDIV(Ww * 192, 256), 256, 0, stream>>>(DinvT);
    build_lf   <<<CDIV(S2 * LMAX * 192, 256), 256, 0, stream>>>(leg_fwd, LF);
    build_lit  <<<CDIV(MMAX * Hh * 96, 256), 256, 0, stream>>>(leg_inv, LIT);
    conv_mat<<<CDIV(256 * 256, 256), 256, 0, stream>>>(enc_w2, ENC2B, 256, 256, 256);
    conv_mat<<<CDIV(256 * 256, 256), 256, 0, stream>>>(dec_w1, DW1B, 256, 256, Ech + CIN);
    conv_mat<<<CDIV(2 * 256, 256), 256, 0, stream>>>(dec_w2, DW2B, 2, 256, 256);

    // ---------------- encoder ----------------
    // V1 = gelu(enc_w1 @ x)  (fp32, K=2)
    gemm(stream, enc_w1, x, V1, nullptr, Ech, NPIX, CIN, 1,
         0, CIN, 1,  0, NPIX, 1,  0, NPIX, 1,  0, 0, 0,  1.0f, 2);
    // V1PB = V1^T (bf16, pixel-major)
    tcv(stream, V1, V1PB, 256, NPIX, 0, NPIX, 0, 256, 1, 1.0f);
    // HC = enc_w2 @ V1 + pos
    gemmb(stream, ENC2B, 256, 0, V1PB, 256, 0, HC, 0, NPIX, 1,
          pos, 0, NPIX, 1, 256, NPIX, 256, 1, 1);

    float* curH = HC;
    float* curN = HC2;

    for (int l = 0; l < NLAYERS; ++l) {
        const float* wr_l = w_spec_r + (ll)l * EE * LMAX;
        const float* wi_l = w_spec_i + (ll)l * EE * LMAX;

        // per-layer weight converts
        conv_mat<<<CDIV(256 * 256, 256), 256, 0, stream>>>(w_inner + (ll)l * EE, WINB, 256, 256, 256);
        conv_mat<<<CDIV(512 * 256, 256), 256, 0, stream>>>(w_mlp1 + (ll)l * HIDD * Ech, WM1B, 512, 256, 256);
        conv_mat<<<CDIV(256 * 512, 256), 256, 0, stream>>>(w_mlp2 + (ll)l * Ech * HIDD, WM2B, 256, 512, 512);

        // 1. HCB = pad(HC) bf16  [46080][384]
        conv_pad<<<CDIV(46080LL * 384, 256), 256, 0, stream>>>(curH, HCB, CHROWS, Ww, 384);
        // 2. rfft: XF[(ch)][s] = HCB @ DmT^T   M=46080 N=182 K=384
        gemmb(stream, HCB, 384, 0, DmT, 384, 0, XF, 0, 182, 1,
              nullptr, 0, 0, 0, CHROWS, S2, 384, 1, 0);
        // 3. XT[s][c][h] (bf16, h padded to 192)
        zero_pad<<<CDIV(46592LL * 12, 256), 256, 0, stream>>>(XT, 46592LL, 192, 180, 192);
        tcv(stream, XF, XT, Hh, S2, (ll)Hh * S2, S2, 192, 49152, 256, 1.0f);
        // 4. Legendre fwd: CF[s][c][l] : z=182, M=256 N=90 K=192
        gemmb(stream, XT, 192, 49152, LF, 192, 17280, CF, 23040, 90, 1,
              nullptr, 0, 0, 0, 256, LMAX, 192, 182, 0);
        // 5. TCF[l][m][(p,c)] bf16 (two p-halves)
        for (int pp = 0; pp < 2; ++pp)
            tcv(stream, CF + (ll)pp * 2096640, TCF + (ll)pp * 256, 256, LMAX,
                23040, LMAX, 512, 46592, MMAX, 1.0f);
        // 6. WC[l][o'][cp] = [[Wr, -Wi],[Wi, Wr]] bf16
        tcv(stream, wr_l, WC,                256, LMAX, 23040, LMAX, 512, 262144, 256,  1.0f);
        tcv(stream, wi_l, WC + 256,          256, LMAX, 23040, LMAX, 512, 262144, 256, -1.0f);
        tcv(stream, wi_l, WC + 131072,       256, LMAX, 23040, LMAX, 512, 262144, 256,  1.0f);
        tcv(stream, wr_l, WC + 131072 + 256, 256, LMAX, 23040, LMAX, 512, 262144, 256,  1.0f);
        // 7. spectral filter: CO[l][o'][m] : z=90, M=512 N=91 K=512
        gemmb(stream, WC, 512, 262144, TCF, 512, 46592, CO, 46592, 91, 1,
              nullptr, 0, 0, 0, 512, MMAX, 512, LMAX, 0);
        // 8. COT[m][o'][l] bf16 (l padded to 96)
        zero_pad<<<CDIV(46592LL * 6, 256), 256, 0, stream>>>(COT, 46592LL, 96, 90, 96);
        tcv(stream, CO, COT, LMAX, MMAX, 91, 46592, 96, 49152, 512, 1.0f);
        // 9. Legendre inv: YT[m][o'][h] : z=91, M=512 N=180 K=96
        gemmb(stream, COT, 96, 49152, LIT, 96, 17280, YT, 92160, 180, 1,
              nullptr, 0, 0, 0, 512, Hh, 96, MMAX, 0);
        // 10. YF[(oh)][s] bf16 (s padded to 192)
        zero_pad<<<CDIV(46080LL * 10, 256), 256, 0, stream>>>(YF, 46080LL, 192, 182, 192);
        for (int pp = 0; pp < 2; ++pp)
            tcv(stream, YT + (ll)pp * 46080, YF + (ll)pp * 91, MMAX, CHROWS,
                0, 92160, 0, 192, 1, 1.0f);
        // 11. irfft: VF[c][(hw)] = YF @ DinvT^T : M=46080 N=360 K=192
        gemmb(stream, YF, 192, 0, DinvT, 192, 0, VF, 0, 360, 1,
              nullptr, 0, 0, 0, CHROWS, Ww, 192, 1, 0);
        // 12. HPB = HC^T bf16
        tcv(stream, curH, HPB, 256, NPIX, 0, NPIX, 0, 256, 1, 1.0f);
        // 13. inner skip: VF = w_inner@h + VF  (in place, 1:1 element map)
        gemmb(stream, WINB, 256, 0, HPB, 256, 0, VF, 0, NPIX, 1,
              VF, 0, NPIX, 1, 256, NPIX, 256, 1, 1);
        // 14. V2PB = VF^T bf16
        tcv(stream, VF, V2PB, 256, NPIX, 0, NPIX, 0, 256, 1, 1.0f);
        // 15. mlp1: GT[(hw)][hid] = gelu(V2PB @ WM1B^T), bf16 out : M=64800 N=512 K=256
        gemmb(stream, V2PB, 256, 0, WM1B, 256, 0, GT, 0, 512, 1,
              nullptr, 0, 0, 0, NPIX, HIDD, 256, 1, 6);
        // 16. mlp2 + residual: HC_next[c][(hw)] = WM2B @ GT^T + HC : M=256 N=64800 K=512
        gemmb(stream, WM2B, 512, 0, GT, 512, 0, curN, 0, NPIX, 1,
              curH, 0, NPIX, 1, 256, NPIX, 512, 1, 1);

        float* tmp = curH; curH = curN; curN = tmp;
    }

    // ---------------- decoder ----------------
    __hip_bfloat16* HPBd = (__hip_bfloat16*)(pool + 0);
    float* T2 = VF;   // [256][64800] f32
    // HPBd = h^T bf16
    tcv(stream, curH, HPBd, 256, NPIX, 0, NPIX, 0, 256, 1, 1.0f);
    // T2 = dec_w1[:, :256] @ h
    gemmb(stream, DW1B, 256, 0, HPBd, 256, 0, T2, 0, NPIX, 1,
          nullptr, 0, 0, 0, 256, NPIX, 256, 1, 0);
    // T2 = gelu(dec_w1[:, 256:] @ x + T2)   (fp32, K=2, in place 1:1)
    gemm(stream, dec_w1 + Ech, x, T2, T2, Ech, NPIX, CIN, 1,
         0, Ech + CIN, 1,  0, NPIX, 1,  0, NPIX, 1,  0, NPIX, 1,  1.0f, 3);
    // T2PB = T2^T bf16
    __hip_bfloat16* T2PB = (__hip_bfloat16*)(pool + 0);
    tcv(stream, T2, T2PB, 256, NPIX, 0, NPIX, 0, 256, 1, 1.0f);
    // out[(hw) x 2 -> stored [2][(hw)]] = T2PB @ DW2B^T : M=64800 N=2 K=256
    gemmb(stream, T2PB, 256, 0, DW2B, 256, 0, out, 0, 1, NPIX,
          nullptr, 0, 0, 0, NPIX, COUTC, 256, 1, 0);
}